// Round 4
// baseline (187.235 us; speedup 1.0000x reference)
//
#include <hip/hip_runtime.h>
#include <math.h>

#define NN 16777216
#define KBINS 5
#define TBOUND 2.5f

// 2048 blocks x 256 threads = 524288 threads; NN/4 = 4194304 float4 -> exactly 8 per thread.
#define NBLOCKS 2048
#define NTHREADS 256
#define ITERS 8

typedef float f32x4 __attribute__((ext_vector_type(4)));

// Per-bin tables packed for single ds_read_b128 lookups:
//   t0[b] = { cw[b],  1/(cw[b+1]-cw[b]+1e-8),  s_k=H/W,  2*log(s_k+1e-8) }
//   t1[b] = { ch[b],  ch[b+1]-ch[b],           D[b],     D[b+1]          }

__device__ __forceinline__ float2 rqs1(float x,
                                       float c1, float c2, float c3, float c4,
                                       const f32x4* __restrict__ t0,
                                       const f32x4* __restrict__ t1) {
    bool inside = (x >= -TBOUND) && (x <= TBOUND);
    float xs = inside ? x : 0.0f;
    // searchsorted(cum_w[1:-1], xs, 'left') == count of boundaries < xs
    int b = (int)(xs > c1) + (int)(xs > c2) + (int)(xs > c3) + (int)(xs > c4);
    f32x4 a  = t0[b];
    f32x4 cc = t1[b];
    float xi = (xs - a.x) * a.y;
    xi = fminf(fmaxf(xi, 0.0f), 1.0f);
    float omxi = 1.0f - xi;
    float xo   = xi * omxi;
    float sk = a.z;
    float dk = cc.z, dk1 = cc.w;
    float denom = fmaf(dk + dk1 - 2.0f * sk, xo, sk);
    float num   = fmaf(sk * xi, xi, dk * xo);
    // fast reciprocal (1 ulp) instead of precise div: threshold is 1e-1
    float zin   = fmaf(cc.y * num, __builtin_amdgcn_rcpf(denom + 1e-8f), cc.x);
    float numj  = fmaf(dk1 * xi, xi, fmaf(2.0f * sk, xo, dk * omxi * omxi));
    // lj = a.w + ln(numj+eps) - 2*ln(|denom|+eps)  via two raw v_log_f32 (log2) + one fma
    float l1 = __builtin_amdgcn_logf(numj + 1e-8f);
    float l2 = __builtin_amdgcn_logf(fabsf(denom) + 1e-8f);
    float ljin = fmaf(0.69314718056f, fmaf(-2.0f, l2, l1), a.w);
    float2 r;
    r.x = inside ? zin  : x;
    r.y = inside ? ljin : 0.0f;
    return r;
}

__global__ __launch_bounds__(NTHREADS) void rqs_kernel(const float* __restrict__ x,
                                                       const float* __restrict__ params,
                                                       float* __restrict__ out) {
    __shared__ f32x4 t0[KBINS];
    __shared__ f32x4 t1[KBINS];
    __shared__ float cwS[KBINS + 1];

    if (threadIdx.x == 0) {
        float p[3 * KBINS + 1];
        #pragma unroll
        for (int i = 0; i < 3 * KBINS + 1; ++i) p[i] = params[i];

        // softmax(widths) * 2*TB
        float mw = p[0];
        #pragma unroll
        for (int i = 1; i < KBINS; ++i) mw = fmaxf(mw, p[i]);
        float ew[KBINS]; float sw = 0.0f;
        #pragma unroll
        for (int i = 0; i < KBINS; ++i) { ew[i] = __expf(p[i] - mw); sw += ew[i]; }
        float W[KBINS];
        #pragma unroll
        for (int i = 0; i < KBINS; ++i) W[i] = ew[i] / sw * (2.0f * TBOUND);

        // softmax(heights) * 2*TB
        float mh = p[KBINS];
        #pragma unroll
        for (int i = 1; i < KBINS; ++i) mh = fmaxf(mh, p[KBINS + i]);
        float eh[KBINS]; float sh = 0.0f;
        #pragma unroll
        for (int i = 0; i < KBINS; ++i) { eh[i] = __expf(p[KBINS + i] - mh); sh += eh[i]; }
        float H[KBINS];
        #pragma unroll
        for (int i = 0; i < KBINS; ++i) H[i] = eh[i] / sh * (2.0f * TBOUND);

        // softplus(derivs) + 1e-5  (numerically safe form)
        float D[KBINS + 1];
        #pragma unroll
        for (int i = 0; i < KBINS + 1; ++i) {
            float v = p[2 * KBINS + i];
            D[i] = fmaxf(v, 0.0f) + log1pf(__expf(-fabsf(v))) + 1e-5f;
        }

        // cumulative knots
        float cw[KBINS + 1], ch[KBINS + 1];
        cw[0] = -TBOUND; ch[0] = -TBOUND;
        float aw = 0.0f, ah = 0.0f;
        #pragma unroll
        for (int i = 0; i < KBINS; ++i) {
            aw += W[i]; cw[i + 1] = -TBOUND + aw;
            ah += H[i]; ch[i + 1] = -TBOUND + ah;
        }

        #pragma unroll
        for (int b = 0; b < KBINS; ++b) {
            float sk = H[b] / W[b];
            f32x4 v0 = { cw[b], 1.0f / (cw[b + 1] - cw[b] + 1e-8f), sk, 2.0f * logf(sk + 1e-8f) };
            f32x4 v1 = { ch[b], ch[b + 1] - ch[b], D[b], D[b + 1] };
            t0[b] = v0;
            t1[b] = v1;
        }
        #pragma unroll
        for (int i = 0; i < KBINS + 1; ++i) cwS[i] = cw[i];
    }
    __syncthreads();

    // loop-invariant interior boundaries -> registers
    float c1 = cwS[1], c2 = cwS[2], c3 = cwS[3], c4 = cwS[4];

    const f32x4* __restrict__ xv  = (const f32x4*)x;
    f32x4* __restrict__ zv  = (f32x4*)out;
    f32x4* __restrict__ ljv = (f32x4*)(out + NN);

    const int tid    = blockIdx.x * blockDim.x + threadIdx.x;
    const int stride = NBLOCKS * NTHREADS;

    // Full unroll: all 8 strided loads issued up front (8x global_load_dwordx4 in flight)
    f32x4 xx[ITERS];
    #pragma unroll
    for (int k = 0; k < ITERS; ++k)
        xx[k] = __builtin_nontemporal_load(xv + tid + k * stride);

    #pragma unroll
    for (int k = 0; k < ITERS; ++k) {
        int i = tid + k * stride;
        float2 r0 = rqs1(xx[k].x, c1, c2, c3, c4, t0, t1);
        float2 r1 = rqs1(xx[k].y, c1, c2, c3, c4, t0, t1);
        float2 r2 = rqs1(xx[k].z, c1, c2, c3, c4, t0, t1);
        float2 r3 = rqs1(xx[k].w, c1, c2, c3, c4, t0, t1);
        f32x4 zo = { r0.x, r1.x, r2.x, r3.x };
        f32x4 lo = { r0.y, r1.y, r2.y, r3.y };
        __builtin_nontemporal_store(zo, zv + i);
        __builtin_nontemporal_store(lo, ljv + i);
    }
}

extern "C" void kernel_launch(void* const* d_in, const int* in_sizes, int n_in,
                              void* d_out, int out_size, void* d_ws, size_t ws_size,
                              hipStream_t stream) {
    const float* x      = (const float*)d_in[0];
    const float* params = (const float*)d_in[1];
    float* out          = (float*)d_out;
    rqs_kernel<<<dim3(NBLOCKS), dim3(NTHREADS), 0, stream>>>(x, params, out);
}